// Round 11
// baseline (533.099 us; speedup 1.0000x reference)
//
#include <hip/hip_runtime.h>
#include <hip/hip_bf16.h>

#define NN 100000
#define NE 1000000
#define HD 64
#define NB 98                       // dst buckets of 1024 nodes
#define BSH 10
#define BCAP 12288                  // bin capacity (avg 10240, +20 sigma)
#define EPB 8192                    // edges per k_bin block
#define NB1 ((NE + EPB - 1) / EPB)  // 123
#define NSL 4                       // feature slabs (16 feats = 32 B rows)
#define RSTR (NN + 1)               // per-slab row stride (row NN = dummy zeros)
#define BCAPP 4096                  // per-bucket pad slack
#define NBW ((NN + 63) / 64)        // 64-node batches per slab queue (1563)

typedef unsigned short u16;
typedef unsigned int u32;
typedef unsigned long long u64;
typedef int  __attribute__((ext_vector_type(4))) i32x4;   // clang vector: ok for nontemporal builtins
typedef unsigned int __attribute__((ext_vector_type(4))) u32x4;

__device__ __forceinline__ u16 f2b(float f) {
    __hip_bfloat16 h = __float2bfloat16(f);   // RNE
    return *reinterpret_cast<u16*>(&h);
}
__device__ __forceinline__ float uaf(u32 u) { return __uint_as_float(u); }
__device__ __forceinline__ void acc8(float* a, uint4 v) {
    a[0] += uaf(v.x << 16); a[1] += uaf(v.x & 0xffff0000u);
    a[2] += uaf(v.y << 16); a[3] += uaf(v.y & 0xffff0000u);
    a[4] += uaf(v.z << 16); a[5] += uaf(v.z & 0xffff0000u);
    a[6] += uaf(v.w << 16); a[7] += uaf(v.w & 0xffff0000u);
}

// ---------------- CSR build: bucketed counting sort (u32-packed bins) ----------------

__global__ __launch_bounds__(256) void k_bin(const int* __restrict__ ei,
                                             int* __restrict__ bfill,
                                             u32* __restrict__ bins) {
    __shared__ int hist[NB];
    __shared__ int base[NB];
    int tid = threadIdx.x;
    for (int i = tid; i < NB; i += 256) hist[i] = 0;
    __syncthreads();
    int e0 = blockIdx.x * EPB;
    int n = min(EPB, NE - e0);
    for (int i = tid; i < n; i += 256)
        atomicAdd(&hist[ei[NE + e0 + i] >> BSH], 1);
    __syncthreads();
    for (int i = tid; i < NB; i += 256) {
        int c = hist[i];
        base[i] = c ? atomicAdd(&bfill[i], c) : 0;
        hist[i] = 0;
    }
    __syncthreads();
    for (int i = tid; i < n; i += 256) {
        int s = ei[e0 + i];
        int d = ei[NE + e0 + i];
        int g = d >> BSH;
        int pos = base[g] + atomicAdd(&hist[g], 1);
        bins[(size_t)g * BCAP + min(pos, BCAP - 1)] = ((u32)(d & 1023) << 17) | (u32)s;
    }
}

// per bucket: rowptr (x4-aligned, padded rows), plen, self-loop+pads, dis, xs,
// XCD-local edge scatter, dummy-row zeroing. col stores src INDEX (pad = NN).
__global__ __launch_bounds__(1024) void k_build(const u32* __restrict__ bins,
        const int* __restrict__ bfill,
        int* __restrict__ rowptr, int* __restrict__ plen, int* __restrict__ col,
        const float2* __restrict__ x2, float* __restrict__ dis,
        float2* __restrict__ xs, u16* __restrict__ T) {
    __shared__ int cnt[1024];
    __shared__ int rof[1024];
    __shared__ int wsum[16];
    __shared__ int gbase_sh;
    int g = blockIdx.x, tid = threadIdx.x;
    int lane = tid & 63, w = tid >> 6;

    // bucket base = sum_{t<g} (align4(bfill[t]) + BCAPP)   (x4-aligned)
    int part = (tid < g) ? (((bfill[tid] + 3) & ~3) + BCAPP) : 0;
#pragma unroll
    for (int off = 32; off; off >>= 1) part += __shfl_xor(part, off);
    if (lane == 0) wsum[w] = part;
    cnt[tid] = 0;
    __syncthreads();
    if (tid == 0) {
        int s = 0;
#pragma unroll
        for (int i = 0; i < 16; ++i) s += wsum[i];
        gbase_sh = s;
    }
    __syncthreads();
    int gbase = gbase_sh;

    int n = min(bfill[g], BCAP);
    const u32* bp = bins + (size_t)g * BCAP;
    for (int i = tid; i < n; i += 1024)
        atomicAdd(&cnt[bp[i] >> 17], 1);
    __syncthreads();

    int node = (g << BSH) + tid;
    int c = cnt[tid];
    int pc = (node < NN) ? ((c + 1 + 3) & ~3) : 0;   // row len padded to x4

    int s = pc;
#pragma unroll
    for (int off = 1; off < 64; off <<= 1) { int t = __shfl_up(s, off); if (lane >= off) s += t; }
    if (lane == 63) wsum[w] = s;
    __syncthreads();
    if (tid < 16) {
        int ws = wsum[tid];
#pragma unroll
        for (int off = 1; off < 16; off <<= 1) { int t = __shfl_up(ws, off); if (tid >= off) ws += t; }
        wsum[tid] = ws;
    }
    __syncthreads();
    int r = gbase + (w ? wsum[w - 1] : 0) + s - pc;
    rof[tid] = r;
    if (node < NN) {
        rowptr[node] = r;
        plen[node] = pc;
        col[r] = node;                          // self-loop at slot 0
        for (int t = c + 1; t < pc; ++t) col[r + t] = NN;   // pads -> dummy row
        float dd = rsqrtf((float)(c + 1));
        dis[node] = dd;
        float2 xv = x2[node];
        xs[node] = make_float2(xv.x * dd, xv.y * dd);
    }
    cnt[tid] = 1;                               // fill counter (slot 0 taken)
    __syncthreads();

    for (int i = tid; i < n; i += 1024) {
        u32 v = bp[i];
        int dloc = v >> 17;
        int src = (int)(v & 0x1ffffu);
        int local = atomicAdd(&cnt[dloc], 1);
        col[rof[dloc] + local] = src;
    }

    if (g == 0) {
        // zero dummy row NN of each slab of T
        if (tid < NSL * 16) T[((size_t)(tid >> 4) * RSTR + NN) * 16 + (tid & 15)] = 0;
        if (tid == 0) xs[NN] = make_float2(0.f, 0.f);
    }
}

// ---------------- layer 1: aggregate xs [N,2] then transform by W1 ----------------
// h layout (h1/h2/T): feat F of node n at byte ((F>>4)*RSTR + n)*32 + (F&15)*2

__global__ __launch_bounds__(256) void k_layer1(const float2* __restrict__ xs,
        const int* __restrict__ rowptr, const int* __restrict__ plen,
        const int* __restrict__ col,
        const float* __restrict__ dis, const float* __restrict__ W1,
        const float* __restrict__ b1, u16* __restrict__ h1) {
    int tid = threadIdx.x, lane = tid & 63, wv = tid >> 6;
    int node = blockIdx.x * 4 + wv;
    if (node >= NN) return;
    int s = rowptr[node], e = s + plen[node];
    float ax = 0.f, ay = 0.f;
    for (int base = s; base < e; base += 64) {
        int idx = base + lane;
        int cvr = col[idx];                 // safe overread (col slack)
        int cv = (idx < e) ? cvr : NN;      // dummy xs[NN] = 0 (pads also NN)
        float2 xv = xs[cv];
        ax += xv.x; ay += xv.y;
    }
#pragma unroll
    for (int off = 32; off; off >>= 1) { ax += __shfl_xor(ax, off); ay += __shfl_xor(ay, off); }
    float dd = dis[node];
    ax *= dd; ay *= dd;
    float o = fmaxf(fmaf(ax, W1[lane], fmaf(ay, W1[HD + lane], b1[lane])), 0.f);
    *(u16*)((char*)h1 + ((size_t)((lane >> 4) * RSTR + node) * 32 + (lane & 15) * 2)) = f2b(o * dd);
}

// ---------------- transform: T = h @ W (both slab-major bf16) ----------------

__global__ __launch_bounds__(256) void k_xf(const u16* __restrict__ hin,
        const float* __restrict__ W, u16* __restrict__ T) {
    int tid = threadIdx.x, lane = tid & 63, wv = tid >> 6;
    int n0 = blockIdx.x * 16 + wv * 4;
    int node = n0 + (lane >> 4);
    int fl = lane & 15;
    u64 v = *(const u64*)((const char*)hin +
            ((size_t)((fl >> 2) * RSTR + node) * 32 + (size_t)(fl & 3) * 8));
    u32 lo = (u32)v, hi = (u32)(v >> 32);
    float hv[4] = { uaf(lo << 16), uaf(lo & 0xffff0000u), uaf(hi << 16), uaf(hi & 0xffff0000u) };
    float o[4] = {0.f, 0.f, 0.f, 0.f};
#pragma unroll
    for (int k = 0; k < HD; ++k) {
        float wk = W[k * HD + lane];
#pragma unroll
        for (int q = 0; q < 4; ++q) {
            float a = __int_as_float(__builtin_amdgcn_readlane(
                __float_as_int(hv[k & 3]), q * 16 + (k >> 2)));
            o[q] = fmaf(a, wk, o[q]);
        }
    }
#pragma unroll
    for (int q = 0; q < 4; ++q)
        *(u16*)((char*)T + ((size_t)((lane >> 4) * RSTR + n0 + q) * 32 + (lane & 15) * 2)) = f2b(o[q]);
}

// ---------------- slab aggregation: XCC-pinned queues + work stealing ----------------
// Wave reads HW_REG_XCC_ID; primary slab = xcc&3 -> T slab stays resident in that
// XCD's L2 (2 XCDs per slab). 64-node batches grabbed by lane0 atomic (no barriers);
// after own queue drains, steal others (coverage correct for ANY block->XCD mapping).
// col loads and output stores are NON-TEMPORAL so streams don't evict the T slab.

template <bool LAST>
__global__ __launch_bounds__(256) void k_agg(const u16* __restrict__ T,
        const int* __restrict__ rowptr, const int* __restrict__ plen,
        const int* __restrict__ col,
        const float* __restrict__ dis, const float* __restrict__ b,
        const float* __restrict__ Wl, u16* __restrict__ hout,
        float* __restrict__ partial, int* __restrict__ q) {
    int lane = threadIdx.x & 63;
    int xcc;
    asm volatile("s_getreg_b32 %0, hwreg(20, 0, 32)" : "=s"(xcc));  // HW_REG_XCC_ID

    for (int so = 0; so < 4; ++so) {
        int slab = (xcc + so) & 3;
        const char* Tb = (const char*)T + (size_t)slab * RSTR * 32;
        for (;;) {
            int t = 0;
            if (lane == 0) t = atomicAdd(q + slab * 16, 1);
            t = __shfl(t, 0);
            if (t >= NBW) break;
            int node = t * 64 + lane;
            if (node >= NN) continue;

            int r = rowptr[node];
            int pl = plen[node];                 // multiple of 4, >= 4
            float acc[16];
#pragma unroll
            for (int j = 0; j < 16; ++j) acc[j] = 0.f;

            int i = 0;
            for (; i + 8 <= pl; i += 8) {
                i32x4 c0 = __builtin_nontemporal_load((const i32x4*)(col + r + i));
                i32x4 c1 = __builtin_nontemporal_load((const i32x4*)(col + r + i + 4));
                const uint4* p0 = (const uint4*)(Tb + (size_t)c0.x * 32);
                const uint4* p1 = (const uint4*)(Tb + (size_t)c0.y * 32);
                const uint4* p2 = (const uint4*)(Tb + (size_t)c0.z * 32);
                const uint4* p3 = (const uint4*)(Tb + (size_t)c0.w * 32);
                const uint4* p4 = (const uint4*)(Tb + (size_t)c1.x * 32);
                const uint4* p5 = (const uint4*)(Tb + (size_t)c1.y * 32);
                const uint4* p6 = (const uint4*)(Tb + (size_t)c1.z * 32);
                const uint4* p7 = (const uint4*)(Tb + (size_t)c1.w * 32);
                uint4 v0a = p0[0], v0b = p0[1];
                uint4 v1a = p1[0], v1b = p1[1];
                uint4 v2a = p2[0], v2b = p2[1];
                uint4 v3a = p3[0], v3b = p3[1];
                uint4 v4a = p4[0], v4b = p4[1];
                uint4 v5a = p5[0], v5b = p5[1];
                uint4 v6a = p6[0], v6b = p6[1];
                uint4 v7a = p7[0], v7b = p7[1];
                acc8(acc, v0a); acc8(acc + 8, v0b);
                acc8(acc, v1a); acc8(acc + 8, v1b);
                acc8(acc, v2a); acc8(acc + 8, v2b);
                acc8(acc, v3a); acc8(acc + 8, v3b);
                acc8(acc, v4a); acc8(acc + 8, v4b);
                acc8(acc, v5a); acc8(acc + 8, v5b);
                acc8(acc, v6a); acc8(acc + 8, v6b);
                acc8(acc, v7a); acc8(acc + 8, v7b);
            }
            if (i < pl) {                        // exactly 4 remain
                i32x4 c0 = __builtin_nontemporal_load((const i32x4*)(col + r + i));
                const uint4* p0 = (const uint4*)(Tb + (size_t)c0.x * 32);
                const uint4* p1 = (const uint4*)(Tb + (size_t)c0.y * 32);
                const uint4* p2 = (const uint4*)(Tb + (size_t)c0.z * 32);
                const uint4* p3 = (const uint4*)(Tb + (size_t)c0.w * 32);
                uint4 v0a = p0[0], v0b = p0[1];
                uint4 v1a = p1[0], v1b = p1[1];
                uint4 v2a = p2[0], v2b = p2[1];
                uint4 v3a = p3[0], v3b = p3[1];
                acc8(acc, v0a); acc8(acc + 8, v0b);
                acc8(acc, v1a); acc8(acc + 8, v1b);
                acc8(acc, v2a); acc8(acc + 8, v2b);
                acc8(acc, v3a); acc8(acc + 8, v3b);
            }

            float dd = dis[node];
            if (!LAST) {
                u32 p[8];
#pragma unroll
                for (int j = 0; j < 8; ++j) {
                    float o0 = fmaxf(fmaf(dd, acc[2 * j],     b[slab * 16 + 2 * j]),     0.f) * dd;
                    float o1 = fmaxf(fmaf(dd, acc[2 * j + 1], b[slab * 16 + 2 * j + 1]), 0.f) * dd;
                    p[j] = (u32)f2b(o0) | ((u32)f2b(o1) << 16);
                }
                char* hb = (char*)hout + ((size_t)slab * RSTR + node) * 32;
                u32x4 w0 = {p[0], p[1], p[2], p[3]};
                u32x4 w1 = {p[4], p[5], p[6], p[7]};
                __builtin_nontemporal_store(w0, (u32x4*)hb);
                __builtin_nontemporal_store(w1, (u32x4*)(hb + 16));
            } else {
                float ps = 0.f;
#pragma unroll
                for (int j = 0; j < 16; ++j)
                    ps = fmaf(fmaxf(fmaf(dd, acc[j], b[slab * 16 + j]), 0.f),
                              Wl[slab * 16 + j], ps);
                __builtin_nontemporal_store(ps, partial + (size_t)slab * NN + node);
            }
        }
    }
}

// ---------------- final: y = sum of 4 slab partials + bl ----------------

__global__ __launch_bounds__(256) void k_fin(const float* __restrict__ partial,
        const float* __restrict__ bl, float* __restrict__ y) {
    int i = blockIdx.x * 256 + threadIdx.x;
    if (i >= NN) return;
    y[i] = partial[i] + partial[NN + i] + partial[2 * NN + i] + partial[3 * NN + i] + bl[0];
}

// ---------------- launch ----------------

extern "C" void kernel_launch(void* const* d_in, const int* in_sizes, int n_in,
                              void* d_out, int out_size, void* d_ws, size_t ws_size,
                              hipStream_t stream) {
    const float* x  = (const float*)d_in[0];
    const int*   ei = (const int*)d_in[1];   // [2,E]: src = ei[0:E], dst = ei[E:2E]
    const float* W1 = (const float*)d_in[2];
    const float* b1 = (const float*)d_in[3];
    const float* W2 = (const float*)d_in[4];
    const float* b2 = (const float*)d_in[5];
    const float* W3 = (const float*)d_in[6];
    const float* b3 = (const float*)d_in[7];
    const float* Wl = (const float*)d_in[8];
    const float* bl = (const float*)d_in[9];

    // workspace layout, 64 B aligned chunks
    char* p = (char*)d_ws;
    auto alloc = [&](size_t bytes) { char* r = p; p += (bytes + 63) & ~63ull; return r; };
    u32*    bins   = (u32*)   alloc((size_t)NB * BCAP * 4);
    int*    bfill  = (int*)   alloc(128 * 4);        // [0..97] bucket fills
    int*    cq     = (int*)   alloc(128 * 4);        // 2 x 4 queues, stride 16
    int*    rowptr = (int*)   alloc((NN + 2) * 4);
    int*    plen   = (int*)   alloc((NN + 2) * 4);
    float*  dis    = (float*) alloc(NN * 4);
    int*    col    = (int*)   alloc((size_t)(NE + NB * BCAPP + 256) * 4);
    float2* xs     = (float2*)alloc((NN + 1) * 8);
    u16*    h1     = (u16*)   alloc((size_t)NSL * RSTR * 16 * 2);
    u16*    h2     = (u16*)   alloc((size_t)NSL * RSTR * 16 * 2);
    u16*    T      = (u16*)   alloc((size_t)NSL * RSTR * 16 * 2);
    float*  partial= (float*) alloc((size_t)NSL * NN * 4);

    (void)hipMemsetAsync(bfill, 0, 256 * sizeof(int), stream);   // bfill + both queue sets
    k_bin  <<<NB1, 256, 0, stream>>>(ei, bfill, bins);
    k_build<<<NB, 1024, 0, stream>>>(bins, bfill, rowptr, plen, col,
                                     (const float2*)x, dis, xs, T);

    k_layer1<<<(NN + 3) / 4, 256, 0, stream>>>(xs, rowptr, plen, col, dis, W1, b1, h1);

    k_xf <<<NN / 16, 256, 0, stream>>>(h1, W2, T);
    k_agg<false><<<2048, 256, 0, stream>>>(T, rowptr, plen, col, dis, b2, nullptr,
                                           h2, nullptr, cq);

    k_xf <<<NN / 16, 256, 0, stream>>>(h2, W3, T);
    k_agg<true ><<<2048, 256, 0, stream>>>(T, rowptr, plen, col, dis, b3, Wl,
                                           nullptr, partial, cq + 64);

    k_fin<<<(NN + 255) / 256, 256, 0, stream>>>(partial, bl, (float*)d_out);
}